// Round 5
// baseline (30.805 us; speedup 1.0000x reference)
//
#include <hip/hip_runtime.h>
#include <hip/hip_bf16.h>
#include <hip/hip_cooperative_groups.h>

namespace cg = cooperative_groups;

// Hierarchical softmax loss, single cooperative dispatch:
//   loss = (1/B) * sum_b sum_{l=0..L-1} softplus(-scores[b, 2^l - 1 + bit_l])
// where bit_l = (class_indices[b] >> (L-1-l)) & 1, L = ceil(log2(V)).
// 64 blocks gather + block-reduce -> partials; grid.sync(); block 0 reduces
// the 64 partials and writes out[0]. No memset node, no atomic-ticket state.

#define NBLK 64

__global__ __launch_bounds__(256) void hsm_coop_kernel(
    const float* __restrict__ scores,
    const int* __restrict__ cls,
    float* __restrict__ out,
    float* __restrict__ partials,
    int B, int V, int code_len, float invB) {

    const int tid = threadIdx.x;
    const int lvl0 = tid & 15;           // level lane within a row's 16 threads
    const int rowInBlk = tid >> 4;       // 16 rows per 256-thread block
    const int rowsPerBlk = blockDim.x >> 4;

    float acc = 0.0f;
    for (int r = blockIdx.x * rowsPerBlk + rowInBlk; r < B;
         r += gridDim.x * rowsPerBlk) {
        const float* row = scores + (size_t)r * (size_t)V;
        const int ci = cls[r];                   // issues concurrently with a,b
        for (int l = lvl0; l < code_len; l += 16) {   // one iter at L=16
            const float a = row[(1 << l) - 1];   // left candidate  (bit==0)
            const float b = row[(1 << l)];       // right candidate (bit==1)
            const int bit = (ci >> (code_len - 1 - l)) & 1;
            const float x = bit ? b : a;
            // softplus(-x) = -log(sigmoid(x)), numerically stable
            acc += log1pf(__expf(-fabsf(x))) + fmaxf(-x, 0.0f);
        }
    }

    // block reduction: 4 waves of 64
    #pragma unroll
    for (int off = 32; off > 0; off >>= 1)
        acc += __shfl_down(acc, off, 64);

    __shared__ float wsum[4];
    const int lane = tid & 63;
    const int wid = tid >> 6;
    if (lane == 0) wsum[wid] = acc;
    __syncthreads();

    if (tid == 0) {
        const float p = wsum[0] + wsum[1] + wsum[2] + wsum[3];
        __hip_atomic_store(&partials[blockIdx.x], p,
                           __ATOMIC_RELEASE, __HIP_MEMORY_SCOPE_AGENT);
    }

    cg::this_grid().sync();

    if (blockIdx.x == 0 && tid < NBLK) {
        float v = __hip_atomic_load(&partials[tid],
                                    __ATOMIC_ACQUIRE, __HIP_MEMORY_SCOPE_AGENT);
        #pragma unroll
        for (int off = 32; off > 0; off >>= 1)
            v += __shfl_down(v, off, 64);
        if (tid == 0) out[0] = v * invB;
    }
}

extern "C" void kernel_launch(void* const* d_in, const int* in_sizes, int n_in,
                              void* d_out, int out_size, void* d_ws, size_t ws_size,
                              hipStream_t stream) {
    const float* scores = (const float*)d_in[0];
    const int* class_indices = (const int*)d_in[1];
    float* out = (float*)d_out;
    float* partials = (float*)d_ws;     // NBLK floats

    int B = in_sizes[1];                                   // class_indices: [B]
    int V = (int)(in_sizes[0] / (size_t)in_sizes[1]);      // scores: [B, V]

    int code_len = 0;
    while ((1LL << code_len) < (long long)V) ++code_len;

    float invB = 1.0f / (float)B;

    void* args[] = { (void*)&scores, (void*)&class_indices, (void*)&out,
                     (void*)&partials, (void*)&B, (void*)&V,
                     (void*)&code_len, (void*)&invB };
    hipLaunchCooperativeKernel((void*)hsm_coop_kernel,
                               dim3(NBLK), dim3(256), args, 0, stream);
}

// Round 6
// 12.223 us; speedup vs baseline: 2.5202x; 2.5202x over previous
//
#include <hip/hip_runtime.h>
#include <hip/hip_bf16.h>

// Hierarchical softmax loss:
//   loss = (1/B) * sum_b sum_{l=0..L-1} softplus(-scores[b, 2^l - 1 + bit_l])
// where bit_l = (class_indices[b] >> (L-1-l)) & 1, L = ceil(log2(V)).
//
// Two-node graph (measured optimum structure): gather kernel (256 one-wave
// blocks) -> partials, then a one-wave reduce kernel. Both candidate columns
// (2^l-1, 2^l) are loaded concurrently with the index load so the critical
// path is ONE cold-HBM round trip. No LDS, no __syncthreads, no atomics.

__global__ __launch_bounds__(64) void hsm_gather_kernel(
    const float* __restrict__ scores,
    const int* __restrict__ cls,
    float* __restrict__ partials,
    int B, int V, int code_len) {

    const int lane = threadIdx.x;        // 0..63
    const int lvl0 = lane & 15;          // level lane within a row's 16 threads
    const int rowInBlk = lane >> 4;      // 4 rows per 64-thread block
    const int r = blockIdx.x * 4 + rowInBlk;

    float acc = 0.0f;
    if (r < B) {
        const float* row = scores + (size_t)r * (size_t)V;
        const int ci = cls[r];                   // issues concurrently with a,b
        for (int l = lvl0; l < code_len; l += 16) {   // one iter at L=16
            const float a = row[(1 << l) - 1];   // left candidate  (bit==0)
            const float b = row[(1 << l)];       // right candidate (bit==1)
            const int bit = (ci >> (code_len - 1 - l)) & 1;
            const float x = bit ? b : a;
            // softplus(-x) = -log(sigmoid(x)), numerically stable
            acc += log1pf(__expf(-fabsf(x))) + fmaxf(-x, 0.0f);
        }
    }

    // single-wave reduction, then one plain store (visible at kernel boundary)
    #pragma unroll
    for (int off = 32; off > 0; off >>= 1)
        acc += __shfl_down(acc, off, 64);
    if (lane == 0) partials[blockIdx.x] = acc;
}

__global__ __launch_bounds__(64) void hsm_final_kernel(
    const float* __restrict__ partials, float* __restrict__ out,
    int nparts, float invB) {
    float v = 0.0f;
    for (int i = threadIdx.x; i < nparts; i += 64)  // 4 independent loads
        v += partials[i];
    #pragma unroll
    for (int off = 32; off > 0; off >>= 1)
        v += __shfl_down(v, off, 64);
    if (threadIdx.x == 0) out[0] = v * invB;
}

extern "C" void kernel_launch(void* const* d_in, const int* in_sizes, int n_in,
                              void* d_out, int out_size, void* d_ws, size_t ws_size,
                              hipStream_t stream) {
    const float* scores = (const float*)d_in[0];
    const int* class_indices = (const int*)d_in[1];
    float* out = (float*)d_out;
    float* partials = (float*)d_ws;

    const int B = in_sizes[1];                               // class_indices: [B]
    const int V = (int)(in_sizes[0] / (size_t)in_sizes[1]);  // scores: [B, V]

    int code_len = 0;
    while ((1LL << code_len) < (long long)V) ++code_len;

    const int grid = (B + 3) / 4;      // 256 one-wave blocks for B=1024
    hsm_gather_kernel<<<grid, 64, 0, stream>>>(scores, class_indices, partials,
                                               B, V, code_len);
    hsm_final_kernel<<<1, 64, 0, stream>>>(partials, out, grid, 1.0f / (float)B);
}

// Round 7
// 11.387 us; speedup vs baseline: 2.7052x; 1.0734x over previous
//
#include <hip/hip_runtime.h>
#include <hip/hip_bf16.h>

// Hierarchical softmax loss:
//   loss = (1/B) * sum_b sum_{l=0..L-1} softplus(-scores[b, 2^l - 1 + bit_l])
// where bit_l = (class_indices[b] >> (L-1-l)) & 1, L = ceil(log2(V)).
//
// Best-measured structure (R1: 64 blocks x 256 threads + 1-wave final) with
// the concurrent-candidate-load tweak: both columns (2^l-1, 2^l) are loaded
// in parallel with the index load, so kernel A's critical path is ONE
// cold-HBM round trip instead of two dependent ones.

__global__ __launch_bounds__(256) void hsm_partial_kernel(
    const float* __restrict__ scores,
    const int* __restrict__ cls,
    float* __restrict__ partials,
    int B, int V, int code_len) {

    const int tid = threadIdx.x;
    const int lvl0 = tid & 15;         // level lane within the row's 16 threads
    const int rowInBlk = tid >> 4;     // 16 rows per block
    const int r = blockIdx.x * 16 + rowInBlk;

    float acc = 0.0f;
    if (r < B) {
        const float* row = scores + (size_t)r * (size_t)V;
        const int ci = cls[r];                   // issues concurrently with a,b
        for (int l = lvl0; l < code_len; l += 16) {   // one iter at L=16
            const float a = row[(1 << l) - 1];   // left candidate  (bit==0)
            const float b = row[(1 << l)];       // right candidate (bit==1)
            const int bit = (ci >> (code_len - 1 - l)) & 1;
            const float x = bit ? b : a;
            // softplus(-x) = -log(sigmoid(x)), numerically stable
            acc += log1pf(__expf(-fabsf(x))) + fmaxf(-x, 0.0f);
        }
    }

    // block reduction: 4 waves of 64
    #pragma unroll
    for (int off = 32; off > 0; off >>= 1)
        acc += __shfl_down(acc, off, 64);

    __shared__ float wsum[4];
    const int lane = tid & 63;
    const int wid = tid >> 6;
    if (lane == 0) wsum[wid] = acc;
    __syncthreads();
    if (tid == 0)
        partials[blockIdx.x] = wsum[0] + wsum[1] + wsum[2] + wsum[3];
}

__global__ __launch_bounds__(64) void hsm_final_kernel(
    const float* __restrict__ partials, float* __restrict__ out,
    int nparts, float invB) {
    float v = 0.0f;
    for (int i = threadIdx.x; i < nparts; i += 64)
        v += partials[i];
    #pragma unroll
    for (int off = 32; off > 0; off >>= 1)
        v += __shfl_down(v, off, 64);
    if (threadIdx.x == 0) out[0] = v * invB;
}

extern "C" void kernel_launch(void* const* d_in, const int* in_sizes, int n_in,
                              void* d_out, int out_size, void* d_ws, size_t ws_size,
                              hipStream_t stream) {
    const float* scores = (const float*)d_in[0];
    const int* class_indices = (const int*)d_in[1];
    float* out = (float*)d_out;
    float* partials = (float*)d_ws;

    const int B = in_sizes[1];                               // class_indices: [B]
    const int V = (int)(in_sizes[0] / (size_t)in_sizes[1]);  // scores: [B, V]

    int code_len = 0;
    while ((1LL << code_len) < (long long)V) ++code_len;

    const int rowsPerBlk = 16;
    const int grid = (B + rowsPerBlk - 1) / rowsPerBlk;      // 64 for B=1024

    hsm_partial_kernel<<<grid, 256, 0, stream>>>(scores, class_indices, partials,
                                                 B, V, code_len);
    hsm_final_kernel<<<1, 64, 0, stream>>>(partials, out, grid, 1.0f / (float)B);
}